// Round 9
// baseline (563.674 us; speedup 1.0000x reference)
//
#include <hip/hip_runtime.h>

// GTN forward, restructured: never materialize H = conv1@conv2 (4096x4096).
// x@H1 = (x@C1)@C2 ; normalize needs only diag(H1) and colsum(H1)=r@C2.
// R9: gemm with COUNTED vmcnt (T4): wait vmcnt(4) for prev-iter loads only,
// raw s_barrier pair, never drain in-loop (R8's __syncthreads drained the
// just-issued prefetch -> no overlap). sparse_y: col-split x2 + 2-deep
// static-slot prefetch. Rest identical to R8.

typedef float  f4v  __attribute__((ext_vector_type(4)));
typedef short  s8v  __attribute__((ext_vector_type(8)));
typedef unsigned short u16;
typedef unsigned int u32;
typedef u32    u2v  __attribute__((ext_vector_type(2)));
typedef u32    u4v  __attribute__((ext_vector_type(4)));

#define NN 4096
#define MM 640   // B*L

__device__ __forceinline__ u16 f2bf(float f){
  unsigned int u = __float_as_uint(f);
  u += 0x7FFFu + ((u>>16)&1u);
  return (u16)(u>>16);
}
__device__ __forceinline__ float bf2f(u16 h){ return __uint_as_float(((unsigned int)h)<<16); }
__device__ __forceinline__ float sigm(float x){ return 1.f/(1.f+__expf(-x)); }

// packed f32x2 -> bf16x2 (RNE), single VALU inst on gfx950
__device__ __forceinline__ u32 pkbf(float lo, float hi){
  u32 r;
  asm("v_cvt_pk_bf16_f32 %0, %1, %2" : "=v"(r) : "v"(lo), "v"(hi));
  return r;
}

__device__ __forceinline__ void gload16(const void* g, void* l){
  __builtin_amdgcn_global_load_lds((const __attribute__((address_space(1))) unsigned int*)g,
                                   (__attribute__((address_space(3))) unsigned int*)l, 16, 0, 0);
}

__device__ __forceinline__ void softmax23(const float* __restrict__ W, float f[2][3]){
  #pragma unroll
  for (int c=0;c<2;c++){
    float a=W[c*3+0], b=W[c*3+1], d=W[c*3+2];
    float m=fmaxf(a,fmaxf(b,d));
    float ea=__expf(a-m), eb=__expf(b-m), ed=__expf(d-m);
    float s=1.f/(ea+eb+ed);
    f[c][0]=ea*s; f[c][1]=eb*s; f[c][2]=ed*s;
  }
}

// Read A once; produce C1 (straight bf16), C2t/C3t (transposed bf16), r=colsum(C1).
__global__ __launch_bounds__(256)
void k_combine_all(const float* __restrict__ A, const float* __restrict__ W1a,
                   const float* __restrict__ W1b, const float* __restrict__ W2,
                   u16* __restrict__ C1, u16* __restrict__ C2t,
                   u16* __restrict__ C3t, float* __restrict__ r)
{
  __shared__ u16 t2[64][72];
  __shared__ u16 t3[64][72];
  __shared__ float rs[2][64];
  const int tid = threadIdx.x, lane = tid&63;
  const int n0 = blockIdx.x*64, m0 = blockIdx.y*64;
  float fa[2][3], fb[2][3], fc[2][3];
  softmax23(W1a, fa); softmax23(W1b, fb); softmax23(W2, fc);
  if (tid < 128) rs[tid>>6][tid&63] = 0.f;
  const int mb = tid>>4, nb = tid&15;
  f4v a0[4], a1[4], a2[4];
  #pragma unroll
  for (int j=0;j<4;j++){
    const float* ap = A + (size_t)(m0+mb*4+j)*NN + n0 + nb*4;
    a0[j] = *(const f4v*)ap;
    a1[j] = *(const f4v*)(ap + (size_t)NN*NN);
    a2[j] = *(const f4v*)(ap + 2*(size_t)NN*NN);
  }
  #pragma unroll
  for (int c=0;c<2;c++){
    float rp[4] = {};
    #pragma unroll
    for (int j=0;j<4;j++){
      f4v v1 = fa[c][0]*a0[j] + fa[c][1]*a1[j] + fa[c][2]*a2[j];
      u2v o = { pkbf(v1[0],v1[1]), pkbf(v1[2],v1[3]) };
      *(u2v*)(C1 + ((size_t)c*NN + m0+mb*4+j)*NN + n0 + nb*4) = o;
      #pragma unroll
      for (int k=0;k<4;k++) rp[k] += v1[k];
    }
    #pragma unroll
    for (int jj=0;jj<4;jj++){
      f4v c2v, c3v;
      #pragma unroll
      for (int j=0;j<4;j++){
        c2v[j] = fb[c][0]*a0[j][jj] + fb[c][1]*a1[j][jj] + fb[c][2]*a2[j][jj];
        c3v[j] = fc[c][0]*a0[j][jj] + fc[c][1]*a1[j][jj] + fc[c][2]*a2[j][jj];
      }
      *(u2v*)&t2[nb*4+jj][mb*4] = (u2v){ pkbf(c2v[0],c2v[1]), pkbf(c2v[2],c2v[3]) };
      *(u2v*)&t3[nb*4+jj][mb*4] = (u2v){ pkbf(c3v[0],c3v[1]), pkbf(c3v[2],c3v[3]) };
    }
    __syncthreads();
    #pragma unroll
    for (int rep=0;rep<2;rep++){
      const int rw = rep*32 + (tid>>3), l8 = tid&7;
      *(u4v*)(C2t + ((size_t)c*NN + n0+rw)*NN + m0 + l8*8) = *(const u4v*)&t2[rw][l8*8];
      *(u4v*)(C3t + ((size_t)c*NN + n0+rw)*NN + m0 + l8*8) = *(const u4v*)&t3[rw][l8*8];
    }
    #pragma unroll
    for (int k=0;k<4;k++){
      float v = rp[k];
      v += __shfl_xor(v,16); v += __shfl_xor(v,32);
      if (lane < 16) atomicAdd(&rs[c][nb*4+k], v);
    }
    __syncthreads();
  }
  if (tid < 128) atomicAdd(&r[(size_t)(tid>>6)*NN + n0 + (tid&63)], rs[tid>>6][tid&63]);
}

// y[c][row][cb..cb+8) = sum over nnz(x[row]) of C1[c][j][cb..]  (x binary, ~2% dense)
// col-split x2 (grid.y), 8 cols/thread/channel, 2-deep static-slot prefetch.
__global__ __launch_bounds__(256)
void k_sparse_y(const float* __restrict__ seqs, const u16* __restrict__ C1,
                u16* __restrict__ y)
{
  __shared__ int idxl[512];
  __shared__ int cnt;
  const int tid = threadIdx.x, row = blockIdx.x;
  if (tid==0) cnt = 0;
  __syncthreads();
  const float* xr = seqs + (size_t)row*NN;
  #pragma unroll
  for (int it=0; it<4; ++it){
    f4v v = *(const f4v*)(xr + it*1024 + tid*4);
    #pragma unroll
    for (int k=0;k<4;k++) if (v[k] > 0.5f){ int p = atomicAdd(&cnt,1); if (p<512) idxl[p] = it*1024+tid*4+k; }
  }
  __syncthreads();
  const int nz = cnt < 512 ? cnt : 512;
  float acc0[8], acc1[8];
  #pragma unroll
  for (int k=0;k<8;k++){ acc0[k]=0.f; acc1[k]=0.f; }
  const int cb = blockIdx.y*2048 + tid*8;
  s8v a0, c0, a1, c1;
  if (nz > 0){
    const u16* r0 = C1 + (size_t)idxl[0]*NN + cb;
    a0 = *(const s8v*)r0; c0 = *(const s8v*)(r0 + (size_t)NN*NN);
  }
  if (nz > 1){
    const u16* r1 = C1 + (size_t)idxl[1]*NN + cb;
    a1 = *(const s8v*)r1; c1 = *(const s8v*)(r1 + (size_t)NN*NN);
  }
  int p = 0;
  for (; p+1 < nz; p += 2){
    s8v ta = a0, tc = c0;
    if (p+2 < nz){
      const u16* rn = C1 + (size_t)idxl[p+2]*NN + cb;
      a0 = *(const s8v*)rn; c0 = *(const s8v*)(rn + (size_t)NN*NN);
    }
    #pragma unroll
    for (int k=0;k<8;k++){ acc0[k] += bf2f((u16)ta[k]); acc1[k] += bf2f((u16)tc[k]); }
    s8v ua = a1, uc = c1;
    if (p+3 < nz){
      const u16* rn = C1 + (size_t)idxl[p+3]*NN + cb;
      a1 = *(const s8v*)rn; c1 = *(const s8v*)(rn + (size_t)NN*NN);
    }
    #pragma unroll
    for (int k=0;k<8;k++){ acc0[k] += bf2f((u16)ua[k]); acc1[k] += bf2f((u16)uc[k]); }
  }
  if (p < nz){
    #pragma unroll
    for (int k=0;k<8;k++){ acc0[k] += bf2f((u16)a0[k]); acc1[k] += bf2f((u16)c0[k]); }
  }
  u4v o0, o1;
  #pragma unroll
  for (int k=0;k<4;k++){
    o0[k] = pkbf(acc0[2*k], acc0[2*k+1]);
    o1[k] = pkbf(acc1[2*k], acc1[2*k+1]);
  }
  *(u4v*)(y + (size_t)row*NN + cb) = o0;
  *(u4v*)(y + (size_t)MM*NN + (size_t)row*NN + cb) = o1;
}

// diag1[c][k] = dot(C1[c][k][:], C2t[c][k][:]) ; deg = dot(r[c], C2t[c][k][:]) - diag
__global__ __launch_bounds__(256)
void k_diagdeg(const u16* __restrict__ C1, const u16* __restrict__ C2t,
               const float* __restrict__ r, float* __restrict__ diag1,
               float* __restrict__ dinv)
{
  const int tid = threadIdx.x, lane = tid&63;
  const int gw = blockIdx.x*4 + (tid>>6);
  const int c = gw>>12, k = gw&4095;
  const u16* p1 = C1  + ((size_t)c*NN + k)*NN;
  const u16* p2 = C2t + ((size_t)c*NN + k)*NN;
  const float* pr = r + (size_t)c*NN;
  float dd = 0.f, dg = 0.f;
  for (int it=0; it<8; ++it){
    const int j = it*512 + lane*8;
    s8v v1 = *(const s8v*)(p1+j);
    s8v v2 = *(const s8v*)(p2+j);
    f4v r0 = *(const f4v*)(pr+j);
    f4v r1 = *(const f4v*)(pr+j+4);
    #pragma unroll
    for (int q=0;q<8;q++){
      float c2 = bf2f((u16)v2[q]);
      dd += bf2f((u16)v1[q]) * c2;
      dg += ((q<4)? r0[q] : r1[q-4]) * c2;
    }
  }
  #pragma unroll
  for (int m=1;m<64;m<<=1){ dd += __shfl_xor(dd, m); dg += __shfl_xor(dg, m); }
  if (lane==0){
    float deg = dg - dd;
    diag1[(size_t)c*NN+k] = dd;
    dinv[(size_t)c*NN+k]  = (deg==0.f) ? 0.f : 1.f/deg;
  }
}

// Split-K GEMM v4: part[c*4+ks] = Xb[c][:, ks*1024:+1024] @ Bt[c][:, same]^T
// 128x128 tile, BK=32, 4 waves, double-buffered LDS, COUNTED vmcnt:
//   STAGE(next)[4 loads] ; s_waitcnt vmcnt(4)  <- prev-iter loads only
//   s_barrier ; ds_read+MFMA ; s_barrier       <- never drain to 0 in-loop
// Grid 1280 flat, XCD decode (n%8==g%8), swizzled LDS (rule #21 pair).
__global__ __launch_bounds__(256)
void k_gemm_sk(const u16* __restrict__ Xb, const u16* __restrict__ Bt,
               float* __restrict__ part)
{
  __shared__ u16 As[2][128*32];
  __shared__ u16 Bs[2][128*32];
  const int tid = threadIdx.x, lane = tid&63, w = tid>>6;
  const int g = blockIdx.x;
  const int xcd = g & 7, q = g >> 3;        // q in [0,160)
  const int m = q % 5, p = q / 5;           // p in [0,32)
  const int nh = p & 3, ks = (p>>2)&3, c = (p>>4)&1;
  const int m0 = m*128, n0 = (nh*8 + xcd)*128, kb = ks*1024;
  const u16* Ab = Xb + (size_t)c*MM*NN;
  const u16* Bb = Bt + (size_t)c*NN*NN;
  const int srow = lane>>2;                  // 0..15
  const int scol = ((lane&3) ^ (srow&3))*8;  // pre-swizzled source col (u16)
  const int fr = lane&15, c0 = lane>>4;      // frag row, k-chunk
  const int wm = (w>>1)*64, wn = (w&1)*64;
  f4v acc[4][4] = {};
  auto STAGE = [&](int buf, int k0){
    #pragma unroll
    for (int i=0;i<2;i++){
      const int rb = i*64 + w*16;
      gload16(Ab + (size_t)(m0 + rb + srow)*NN + k0 + scol, (void*)&As[buf][rb*32]);
      gload16(Bb + (size_t)(n0 + rb + srow)*NN + k0 + scol, (void*)&Bs[buf][rb*32]);
    }
  };
  STAGE(0, kb);                             // 4 loads in flight
  int cur = 0;
  for (int k0=0;k0<1024;k0+=32){
    if (k0+32 < 1024){
      STAGE(cur^1, kb+k0+32);               // +4 -> 8 outstanding
      asm volatile("s_waitcnt vmcnt(4)" ::: "memory");   // prev 4 landed
    } else {
      asm volatile("s_waitcnt vmcnt(0)" ::: "memory");   // epilogue drain
    }
    __builtin_amdgcn_s_barrier();           // all waves: cur buffer ready
    __builtin_amdgcn_sched_barrier(0);      // no ds_read hoist above barrier
    s8v a[4], b[4];
    #pragma unroll
    for (int t=0;t<4;t++){
      const int ra = wm + t*16 + fr;
      a[t] = *(const s8v*)&As[cur][ra*32 + ((c0 ^ (ra&3))*8)];
      const int rb2 = wn + t*16 + fr;
      b[t] = *(const s8v*)&Bs[cur][rb2*32 + ((c0 ^ (rb2&3))*8)];
    }
    #pragma unroll
    for (int i=0;i<4;i++)
      #pragma unroll
      for (int j=0;j<4;j++)
        acc[i][j] = __builtin_amdgcn_mfma_f32_16x16x32_bf16(a[i], b[j], acc[i][j], 0, 0, 0);
    asm volatile("" ::: "memory");          // no sink below barrier
    __builtin_amdgcn_s_barrier();           // reads of cur done -> overwritable
    cur ^= 1;
  }
  float* pb = part + (size_t)(c*4+ks)*MM*NN;
  #pragma unroll
  for (int i=0;i<4;i++){
    #pragma unroll
    for (int j=0;j<4;j++){
      const int col = n0 + wn + j*16 + fr;
      #pragma unroll
      for (int rr=0;rr<4;rr++){
        const int row = m0 + wm + i*16 + (lane>>4)*4 + rr;
        pb[(size_t)row*NN + col] = acc[i][j][rr];
      }
    }
  }
}

// Sum 4 K-split partials + epilogue -> bf16.
// M==1: u = (z - x*diag)*dinv.  M==2: e relu fusion (channel-0 differs).
template<int M>
__global__ __launch_bounds__(256)
void k_epi(const float* __restrict__ part, const float* __restrict__ seqs,
           const float* __restrict__ diag1, const float* __restrict__ dinv,
           const float* __restrict__ IB, u16* __restrict__ outp)
{
  const int g = blockIdx.x*256 + threadIdx.x;
  const int c = blockIdx.y;
  const int row = g>>10, col = (g&1023)*4;
  const size_t base = (size_t)row*NN + col;
  f4v z = {0.f,0.f,0.f,0.f};
  #pragma unroll
  for (int ks=0;ks<4;ks++)
    z += *(const f4v*)(part + (size_t)(c*4+ks)*MM*NN + base);
  f4v val;
  if constexpr(M==1){
    f4v x  = *(const f4v*)(seqs + base);
    f4v d  = *(const f4v*)(diag1 + (size_t)c*NN + col);
    f4v dv = *(const f4v*)(dinv  + (size_t)c*NN + col);
    val = (z - x*d) * dv;
  } else {
    f4v x  = *(const f4v*)(seqs + base);
    f4v ib = *(const f4v*)(IB + col);
    #pragma unroll
    for (int k=0;k<4;k++){
      float xh = fmaxf(z[k], 0.f);
      float vv = fmaxf(ib[k], 0.f);
      val[k] = (c==0) ? (fmaxf(x[k]*vv,0.f) + xh) : fmaxf(x[k]*vv + xh, 0.f);
    }
  }
  u2v o = { pkbf(val[0],val[1]), pkbf(val[2],val[3]) };
  *(u2v*)(outp + (size_t)c*MM*NN + base) = o;
}

// fp32 -> bf16 for lin_w (2*128*4096) and W_hh (512*128)
__global__ __launch_bounds__(256)
void k_cvt(const float* __restrict__ linw, const float* __restrict__ whh,
           u16* __restrict__ linwb, u16* __restrict__ whhb)
{
  const int g = blockIdx.x*256 + threadIdx.x;
  const int i = g*4;
  const int NL = 2*128*NN;
  f4v v; u16* dst;
  if (i < NL){ v = *(const f4v*)(linw + i); dst = linwb + i; }
  else       { v = *(const f4v*)(whh + (i-NL)); dst = whhb + (i-NL); }
  u2v o = { pkbf(v[0],v[1]), pkbf(v[2],v[3]) };
  *(u2v*)dst = o;
}

// enc_raw[row][c*128+d] += e[c] @ lin_w[c]^T  (K-split x16, atomic accumulate)
__global__ __launch_bounds__(256)
void k_lin(const u16* __restrict__ e, const u16* __restrict__ linwb,
           float* __restrict__ encr)
{
  __shared__ u16 As[64*32];
  __shared__ u16 Bs[64*32];
  const int tid=threadIdx.x, lane=tid&63, w=tid>>6;
  const int m0 = blockIdx.x*64, d0 = blockIdx.y*64;
  const int c = blockIdx.z>>4, ks = blockIdx.z&15;
  const u16* Ab = e + (size_t)c*MM*NN;
  const u16* Bb = linwb + (size_t)c*128*NN;
  const int srow=lane>>2, skof=(lane&3)*8, fr=lane&15, fk=(lane>>4)*8;
  const int wm=(w>>1)*32, wn=(w&1)*32;
  f4v acc[2][2];
  #pragma unroll
  for (int i=0;i<2;i++)
    #pragma unroll
    for (int j=0;j<2;j++) acc[i][j] = (f4v){0.f,0.f,0.f,0.f};
  for (int ki=0;ki<8;++ki){
    const int k0 = ks*256 + ki*32;
    gload16(Ab + (size_t)(m0 + w*16 + srow)*NN + k0 + skof, (void*)&As[(w*16)*32]);
    gload16(Bb + (size_t)(d0 + w*16 + srow)*NN + k0 + skof, (void*)&Bs[(w*16)*32]);
    __syncthreads();
    s8v a[2], b[2];
    #pragma unroll
    for (int t=0;t<2;t++) a[t] = *(const s8v*)&As[(wm+t*16+fr)*32+fk];
    #pragma unroll
    for (int t=0;t<2;t++) b[t] = *(const s8v*)&Bs[(wn+t*16+fr)*32+fk];
    #pragma unroll
    for (int i=0;i<2;i++)
      #pragma unroll
      for (int j=0;j<2;j++)
        acc[i][j] = __builtin_amdgcn_mfma_f32_16x16x32_bf16(a[i], b[j], acc[i][j], 0, 0, 0);
    __syncthreads();
  }
  #pragma unroll
  for (int i=0;i<2;i++)
    #pragma unroll
    for (int j=0;j<2;j++){
      const int col = d0 + wn + j*16 + fr;
      #pragma unroll
      for (int rr=0;rr<4;rr++){
        const int row = m0 + wm + i*16 + (lane>>4)*4 + rr;
        atomicAdd(&encr[(size_t)row*256 + c*128 + col], acc[i][j][rr]);
      }
    }
}

// baskets[row][d] = (enc+lin_b) @ proj_w^T + proj_b
__global__ __launch_bounds__(256)
void k_proj(const float* __restrict__ encr, const float* __restrict__ linb,
            const float* __restrict__ pw, const float* __restrict__ pb,
            float* __restrict__ bask)
{
  const int g = blockIdx.x*256 + threadIdx.x;
  const int row = g>>7, d = g&127;
  const float* er = encr + (size_t)row*256;
  const float* wr = pw + (size_t)d*256;
  float acc = pb[d];
  for (int j=0;j<256;j+=4){
    f4v e4 = *(const f4v*)(er+j);
    f4v l4 = *(const f4v*)(linb+j);
    f4v w4 = *(const f4v*)(wr+j);
    acc += (e4[0]+l4[0])*w4[0] + (e4[1]+l4[1])*w4[1] + (e4[2]+l4[2])*w4[2] + (e4[3]+l4[3])*w4[3];
  }
  bask[g] = acc;
}

// xhat[t][b][n] = baskets @ W_ih^T + b_ih + b_hh
__global__ __launch_bounds__(256)
void k_xhat(const float* __restrict__ bask, const float* __restrict__ wih,
            const float* __restrict__ bih, const float* __restrict__ bhh,
            float* __restrict__ xh)
{
  const int g = blockIdx.x*256 + threadIdx.x;
  const int row = g>>9, n = g&511;
  const float* br = bask + (size_t)row*128;
  const float* wr = wih + (size_t)n*128;
  float acc = bih[n] + bhh[n];
  for (int k=0;k<128;k+=4){
    f4v b4=*(const f4v*)(br+k); f4v w4=*(const f4v*)(wr+k);
    acc += b4[0]*w4[0]+b4[1]*w4[1]+b4[2]*w4[2]+b4[3]*w4[3];
  }
  const int b = row/20, t = row%20;
  xh[((size_t)t*32 + b)*512 + n] = acc;
}

// single-block LSTM, 8 waves; W_hh B-frags live in registers across the 20 steps
__global__ __launch_bounds__(512)
void k_lstm(const float* __restrict__ xhat, const u16* __restrict__ whhb,
            const float* __restrict__ h0, const float* __restrict__ c0,
            const int* __restrict__ slen, float* __restrict__ last)
{
  __shared__ float zb[32][512];
  __shared__ float cbuf[32][128];
  __shared__ u16 hb[32][136];
  const int tid = threadIdx.x, lane = tid&63, w = tid>>6;
  for (int i=tid; i<4096; i+=512){ int b=i>>7,u=i&127; cbuf[b][u]=c0[i]; hb[b][u]=f2bf(h0[i]); }
  const int fr = lane&15, fko = (lane>>4)*8;
  s8v bfr[4][4];
  #pragma unroll
  for (int nt=0;nt<4;nt++)
    #pragma unroll
    for (int kf=0;kf<4;kf++)
      bfr[nt][kf] = *(const s8v*)(whhb + (size_t)(w*64 + nt*16 + fr)*128 + kf*32 + fko);
  __syncthreads();
  for (int t=0;t<20;++t){
    s8v af[2][4];
    #pragma unroll
    for (int mt=0;mt<2;mt++)
      #pragma unroll
      for (int kf=0;kf<4;kf++)
        af[mt][kf] = *(const s8v*)&hb[mt*16+fr][kf*32+fko];
    f4v z[2][4];
    #pragma unroll
    for (int mt=0;mt<2;mt++)
      #pragma unroll
      for (int nt=0;nt<4;nt++){
        const int nn2 = w*64 + nt*16 + fr;
        #pragma unroll
        for (int rr=0;rr<4;rr++){
          const int bb = mt*16 + (lane>>4)*4 + rr;
          z[mt][nt][rr] = xhat[((size_t)t*32 + bb)*512 + nn2];
        }
      }
    #pragma unroll
    for (int kf=0;kf<4;kf++)
      #pragma unroll
      for (int mt=0;mt<2;mt++)
        #pragma unroll
        for (int nt=0;nt<4;nt++)
          z[mt][nt] = __builtin_amdgcn_mfma_f32_16x16x32_bf16(af[mt][kf], bfr[nt][kf], z[mt][nt], 0, 0, 0);
    #pragma unroll
    for (int mt=0;mt<2;mt++)
      #pragma unroll
      for (int nt=0;nt<4;nt++){
        const int nn2 = w*64 + nt*16 + fr;
        #pragma unroll
        for (int rr=0;rr<4;rr++){
          const int bb = mt*16 + (lane>>4)*4 + rr;
          zb[bb][nn2] = z[mt][nt][rr];
        }
      }
    __syncthreads();
    for (int p=tid; p<4096; p+=512){
      const int b=p>>7, u=p&127;
      float zi=zb[b][u], zf=zb[b][128+u], zg=zb[b][256+u], zo=zb[b][384+u];
      float ii=sigm(zi), ff=sigm(zf), gg=tanhf(zg), oo=sigm(zo);
      float cn = ff*cbuf[b][u] + ii*gg;
      float hn = oo*tanhf(cn);
      cbuf[b][u]=cn; hb[b][u]=f2bf(hn);
      if (t == slen[b]-1) last[p] = hn;
    }
    __syncthreads();
  }
}

// out[b][n] = sigmoid(last[b].h2w[n]) * ((1-a) + a*relu(I_B[n]))
__global__ __launch_bounds__(256)
void k_final(const float* __restrict__ last, const float* __restrict__ h2w,
             const float* __restrict__ IB, float* __restrict__ out)
{
  __shared__ float ls[128];
  const int b = blockIdx.y;
  const int n = blockIdx.x*256 + threadIdx.x;
  if (threadIdx.x < 128) ls[threadIdx.x] = last[b*128 + threadIdx.x];
  __syncthreads();
  const float* wr = h2w + (size_t)n*128;
  float acc = 0.f;
  for (int k=0;k<128;k+=4){
    f4v w4 = *(const f4v*)(wr+k);
    acc += w4[0]*ls[k] + w4[1]*ls[k+1] + w4[2]*ls[k+2] + w4[3]*ls[k+3];
  }
  const float vn = fmaxf(IB[n], 0.f);
  out[(size_t)b*NN + n] = (0.5f + 0.5f*vn) * sigm(acc);
}

extern "C" void kernel_launch(void* const* d_in, const int* in_sizes, int n_in,
                              void* d_out, int out_size, void* d_ws, size_t ws_size,
                              hipStream_t stream)
{
  const float* A    = (const float*)d_in[0];
  const float* seqs = (const float*)d_in[1];
  const int*   slen = (const int*)  d_in[2];
  const float* h0   = (const float*)d_in[3];
  const float* c0   = (const float*)d_in[4];
  const float* W1a  = (const float*)d_in[5];
  const float* W1b  = (const float*)d_in[6];
  const float* W2   = (const float*)d_in[7];
  const float* IB   = (const float*)d_in[8];
  const float* linw = (const float*)d_in[9];
  const float* linb = (const float*)d_in[10];
  const float* pw   = (const float*)d_in[11];
  const float* pb   = (const float*)d_in[12];
  const float* wih  = (const float*)d_in[13];
  const float* whh  = (const float*)d_in[14];
  const float* bih  = (const float*)d_in[15];
  const float* bhh  = (const float*)d_in[16];
  const float* h2w  = (const float*)d_in[17];
  (void)in_sizes; (void)n_in; (void)out_size; (void)ws_size;

  char* ws = (char*)d_ws;
  size_t off = 0;
  auto alloc = [&](size_t sz)->void*{ void* p = ws + off; off += (sz + 255) & ~(size_t)255; return p; };
  u16*   C1    = (u16*)  alloc((size_t)2*NN*NN*2);
  u16*   C2t   = (u16*)  alloc((size_t)2*NN*NN*2);
  u16*   C3t   = (u16*)  alloc((size_t)2*NN*NN*2);
  u16*   y     = (u16*)  alloc((size_t)2*MM*NN*2);   // reused as e
  u16*   u     = (u16*)  alloc((size_t)2*MM*NN*2);
  float* part  = (float*)alloc((size_t)4*2*MM*NN*4); // 84 MB fp32 partials
  float* r     = (float*)alloc((size_t)2*NN*4);
  float* diag1 = (float*)alloc((size_t)2*NN*4);
  float* dinv  = (float*)alloc((size_t)2*NN*4);
  u16*   linwb = (u16*)  alloc((size_t)2*128*NN*2);
  u16*   whhb  = (u16*)  alloc((size_t)512*128*2);
  float* encr  = (float*)alloc((size_t)MM*256*4);
  float* bask  = (float*)alloc((size_t)MM*128*4);
  float* xh    = (float*)alloc((size_t)20*32*512*4);
  float* last  = (float*)alloc((size_t)32*128*4);
  // total ~300 MB

  hipMemsetAsync(r, 0, (size_t)2*NN*4, stream);       // atomically accumulated
  hipMemsetAsync(encr, 0, (size_t)MM*256*4, stream);

  k_combine_all<<<dim3(64,64),256,0,stream>>>(A, W1a, W1b, W2, C1, C2t, C3t, r);
  k_sparse_y<<<dim3(MM,2),256,0,stream>>>(seqs, C1, y);
  k_diagdeg<<<2048,256,0,stream>>>(C1, C2t, r, diag1, dinv);
  k_gemm_sk<<<1280,256,0,stream>>>(y, C2t, part);               // G2: y @ C2
  k_epi<1><<<dim3(2560,2),256,0,stream>>>(part, seqs, diag1, dinv, IB, u);
  k_gemm_sk<<<1280,256,0,stream>>>(u, C3t, part);               // G3: u @ C3
  u16* e = y;                                                   // y dead, alias as e
  k_epi<2><<<dim3(2560,2),256,0,stream>>>(part, seqs, diag1, dinv, IB, e);
  k_cvt<<<1088,256,0,stream>>>(linw, whh, linwb, whhb);
  k_lin<<<dim3(10,2,32),256,0,stream>>>(e, linwb, encr);
  k_proj<<<320,256,0,stream>>>(encr, linb, pw, pb, bask);
  k_xhat<<<1280,256,0,stream>>>(bask, wih, bih, bhh, xh);
  k_lstm<<<1,512,0,stream>>>(xh, whhb, h0, c0, slen, last);
  k_final<<<dim3(16,32),256,0,stream>>>(last, h2w, IB, (float*)d_out);
}

// Round 10
// 556.819 us; speedup vs baseline: 1.0123x; 1.0123x over previous
//
#include <hip/hip_runtime.h>

// GTN forward, restructured: never materialize H = conv1@conv2 (4096x4096).
// x@H1 = (x@C1)@C2 ; normalize needs only diag(H1) and colsum(H1)=r@C2.
// R10: revert R9 (sparse_y back to R8 form; plain __syncthreads 2-phase).
// gemm v5: BM=256 x BN=256 tile (16 waves, wave-tile 64x64), BK=32, dbuf,
// split-K x4, XCD decode. Staged bytes 640->384MB (A-redundancy 32->16,
// B-redundancy 5->3) -- attacks the ~7TB/s staging-bandwidth ceiling that
// explains the 95us/gemm plateau (MfmaUtil/VALU/HBM all idle).

typedef float  f4v  __attribute__((ext_vector_type(4)));
typedef short  s8v  __attribute__((ext_vector_type(8)));
typedef unsigned short u16;
typedef unsigned int u32;
typedef u32    u2v  __attribute__((ext_vector_type(2)));
typedef u32    u4v  __attribute__((ext_vector_type(4)));

#define NN 4096
#define MM 640   // B*L

__device__ __forceinline__ u16 f2bf(float f){
  unsigned int u = __float_as_uint(f);
  u += 0x7FFFu + ((u>>16)&1u);
  return (u16)(u>>16);
}
__device__ __forceinline__ float bf2f(u16 h){ return __uint_as_float(((unsigned int)h)<<16); }
__device__ __forceinline__ float sigm(float x){ return 1.f/(1.f+__expf(-x)); }

// packed f32x2 -> bf16x2 (RNE), single VALU inst on gfx950
__device__ __forceinline__ u32 pkbf(float lo, float hi){
  u32 r;
  asm("v_cvt_pk_bf16_f32 %0, %1, %2" : "=v"(r) : "v"(lo), "v"(hi));
  return r;
}

__device__ __forceinline__ void gload16(const void* g, void* l){
  __builtin_amdgcn_global_load_lds((const __attribute__((address_space(1))) unsigned int*)g,
                                   (__attribute__((address_space(3))) unsigned int*)l, 16, 0, 0);
}

__device__ __forceinline__ void softmax23(const float* __restrict__ W, float f[2][3]){
  #pragma unroll
  for (int c=0;c<2;c++){
    float a=W[c*3+0], b=W[c*3+1], d=W[c*3+2];
    float m=fmaxf(a,fmaxf(b,d));
    float ea=__expf(a-m), eb=__expf(b-m), ed=__expf(d-m);
    float s=1.f/(ea+eb+ed);
    f[c][0]=ea*s; f[c][1]=eb*s; f[c][2]=ed*s;
  }
}

// Read A once; produce C1 (straight bf16), C2t/C3t (transposed bf16), r=colsum(C1).
__global__ __launch_bounds__(256)
void k_combine_all(const float* __restrict__ A, const float* __restrict__ W1a,
                   const float* __restrict__ W1b, const float* __restrict__ W2,
                   u16* __restrict__ C1, u16* __restrict__ C2t,
                   u16* __restrict__ C3t, float* __restrict__ r)
{
  __shared__ u16 t2[64][72];
  __shared__ u16 t3[64][72];
  __shared__ float rs[2][64];
  const int tid = threadIdx.x, lane = tid&63;
  const int n0 = blockIdx.x*64, m0 = blockIdx.y*64;
  float fa[2][3], fb[2][3], fc[2][3];
  softmax23(W1a, fa); softmax23(W1b, fb); softmax23(W2, fc);
  if (tid < 128) rs[tid>>6][tid&63] = 0.f;
  const int mb = tid>>4, nb = tid&15;
  f4v a0[4], a1[4], a2[4];
  #pragma unroll
  for (int j=0;j<4;j++){
    const float* ap = A + (size_t)(m0+mb*4+j)*NN + n0 + nb*4;
    a0[j] = *(const f4v*)ap;
    a1[j] = *(const f4v*)(ap + (size_t)NN*NN);
    a2[j] = *(const f4v*)(ap + 2*(size_t)NN*NN);
  }
  #pragma unroll
  for (int c=0;c<2;c++){
    float rp[4] = {};
    #pragma unroll
    for (int j=0;j<4;j++){
      f4v v1 = fa[c][0]*a0[j] + fa[c][1]*a1[j] + fa[c][2]*a2[j];
      u2v o = { pkbf(v1[0],v1[1]), pkbf(v1[2],v1[3]) };
      *(u2v*)(C1 + ((size_t)c*NN + m0+mb*4+j)*NN + n0 + nb*4) = o;
      #pragma unroll
      for (int k=0;k<4;k++) rp[k] += v1[k];
    }
    #pragma unroll
    for (int jj=0;jj<4;jj++){
      f4v c2v, c3v;
      #pragma unroll
      for (int j=0;j<4;j++){
        c2v[j] = fb[c][0]*a0[j][jj] + fb[c][1]*a1[j][jj] + fb[c][2]*a2[j][jj];
        c3v[j] = fc[c][0]*a0[j][jj] + fc[c][1]*a1[j][jj] + fc[c][2]*a2[j][jj];
      }
      *(u2v*)&t2[nb*4+jj][mb*4] = (u2v){ pkbf(c2v[0],c2v[1]), pkbf(c2v[2],c2v[3]) };
      *(u2v*)&t3[nb*4+jj][mb*4] = (u2v){ pkbf(c3v[0],c3v[1]), pkbf(c3v[2],c3v[3]) };
    }
    __syncthreads();
    #pragma unroll
    for (int rep=0;rep<2;rep++){
      const int rw = rep*32 + (tid>>3), l8 = tid&7;
      *(u4v*)(C2t + ((size_t)c*NN + n0+rw)*NN + m0 + l8*8) = *(const u4v*)&t2[rw][l8*8];
      *(u4v*)(C3t + ((size_t)c*NN + n0+rw)*NN + m0 + l8*8) = *(const u4v*)&t3[rw][l8*8];
    }
    #pragma unroll
    for (int k=0;k<4;k++){
      float v = rp[k];
      v += __shfl_xor(v,16); v += __shfl_xor(v,32);
      if (lane < 16) atomicAdd(&rs[c][nb*4+k], v);
    }
    __syncthreads();
  }
  if (tid < 128) atomicAdd(&r[(size_t)(tid>>6)*NN + n0 + (tid&63)], rs[tid>>6][tid&63]);
}

// y[c][row][:] = sum over nnz(x[row]) of C1[c][j][:]  (x binary, ~2% dense)
// 1 block/row, 16 cols/thread/channel, 1-ahead prefetch (R8 measured form).
__global__ __launch_bounds__(256)
void k_sparse_y(const float* __restrict__ seqs, const u16* __restrict__ C1,
                u16* __restrict__ y)
{
  __shared__ int idxl[512];
  __shared__ int cnt;
  const int tid = threadIdx.x, row = blockIdx.x;
  if (tid==0) cnt = 0;
  __syncthreads();
  const float* xr = seqs + (size_t)row*NN;
  #pragma unroll
  for (int it=0; it<4; ++it){
    f4v v = *(const f4v*)(xr + it*1024 + tid*4);
    #pragma unroll
    for (int k=0;k<4;k++) if (v[k] > 0.5f){ int p = atomicAdd(&cnt,1); if (p<512) idxl[p] = it*1024+tid*4+k; }
  }
  __syncthreads();
  const int nz = cnt < 512 ? cnt : 512;
  float acc0[16], acc1[16];
  #pragma unroll
  for (int k=0;k<16;k++){ acc0[k]=0.f; acc1[k]=0.f; }
  const int cb = tid*16;
  s8v ca, cb8, cc8, cd8;
  if (nz > 0){
    const u16* r0 = C1 + (size_t)idxl[0]*NN + cb;
    const u16* r1 = r0 + (size_t)NN*NN;
    ca=*(const s8v*)r0; cb8=*(const s8v*)(r0+8); cc8=*(const s8v*)r1; cd8=*(const s8v*)(r1+8);
  }
  for (int p=0;p<nz;++p){
    const int pn = (p+1<nz)? p+1 : p;
    const u16* r0 = C1 + (size_t)idxl[pn]*NN + cb;
    const u16* r1 = r0 + (size_t)NN*NN;
    s8v na=*(const s8v*)r0, nb=*(const s8v*)(r0+8), nc=*(const s8v*)r1, nd=*(const s8v*)(r1+8);
    #pragma unroll
    for (int k=0;k<8;k++){
      acc0[k]   += bf2f((u16)ca[k]);
      acc0[8+k] += bf2f((u16)cb8[k]);
      acc1[k]   += bf2f((u16)cc8[k]);
      acc1[8+k] += bf2f((u16)cd8[k]);
    }
    ca=na; cb8=nb; cc8=nc; cd8=nd;
  }
  u4v o0, o1;
  #pragma unroll
  for (int k=0;k<4;k++){
    o0[k] = pkbf(acc0[2*k], acc0[2*k+1]);
    o1[k] = pkbf(acc0[8+2*k], acc0[9+2*k]);
  }
  u16* y0 = y + (size_t)row*NN + cb;
  *(u4v*)y0 = o0; *(u4v*)(y0+8) = o1;
  #pragma unroll
  for (int k=0;k<4;k++){
    o0[k] = pkbf(acc1[2*k], acc1[2*k+1]);
    o1[k] = pkbf(acc1[8+2*k], acc1[9+2*k]);
  }
  u16* y1 = y0 + (size_t)MM*NN;
  *(u4v*)y1 = o0; *(u4v*)(y1+8) = o1;
}

// diag1[c][k] = dot(C1[c][k][:], C2t[c][k][:]) ; deg = dot(r[c], C2t[c][k][:]) - diag
__global__ __launch_bounds__(256)
void k_diagdeg(const u16* __restrict__ C1, const u16* __restrict__ C2t,
               const float* __restrict__ r, float* __restrict__ diag1,
               float* __restrict__ dinv)
{
  const int tid = threadIdx.x, lane = tid&63;
  const int gw = blockIdx.x*4 + (tid>>6);
  const int c = gw>>12, k = gw&4095;
  const u16* p1 = C1  + ((size_t)c*NN + k)*NN;
  const u16* p2 = C2t + ((size_t)c*NN + k)*NN;
  const float* pr = r + (size_t)c*NN;
  float dd = 0.f, dg = 0.f;
  for (int it=0; it<8; ++it){
    const int j = it*512 + lane*8;
    s8v v1 = *(const s8v*)(p1+j);
    s8v v2 = *(const s8v*)(p2+j);
    f4v r0 = *(const f4v*)(pr+j);
    f4v r1 = *(const f4v*)(pr+j+4);
    #pragma unroll
    for (int q=0;q<8;q++){
      float c2 = bf2f((u16)v2[q]);
      dd += bf2f((u16)v1[q]) * c2;
      dg += ((q<4)? r0[q] : r1[q-4]) * c2;
    }
  }
  #pragma unroll
  for (int m=1;m<64;m<<=1){ dd += __shfl_xor(dd, m); dg += __shfl_xor(dg, m); }
  if (lane==0){
    float deg = dg - dd;
    diag1[(size_t)c*NN+k] = dd;
    dinv[(size_t)c*NN+k]  = (deg==0.f) ? 0.f : 1.f/deg;
  }
}

// Split-K GEMM v5: part[c*4+ks] = Xb[c][:, ks*1024:+1024] @ Bt[c][:, same]^T
// BM=256 x BN=256, BK=32, 16 waves (1024 thr), wave-tile 64x64, dbuf 2-phase
// (STAGE(next) before compute, one __syncthreads per K-step). Grid 384 flat,
// XCD decode (n-tile%8 == g%8). A rows >= MM clamped (written rows guarded).
__global__ __launch_bounds__(1024)
void k_gemm_sk(const u16* __restrict__ Xb, const u16* __restrict__ Bt,
               float* __restrict__ part)
{
  __shared__ u16 As[2][256*32];
  __shared__ u16 Bs[2][256*32];
  const int tid = threadIdx.x, lane = tid&63, w = tid>>6;   // w 0..15
  const int g = blockIdx.x;
  const int xcd = g & 7, q = g >> 3;        // q in [0,48)
  const int m = q % 3, p = q / 3;           // p in [0,16)
  const int nh = p & 1, ks = (p>>1)&3, c = (p>>3)&1;
  const int m0 = m*256, n0 = (nh*8 + xcd)*256, kb = ks*1024;
  const u16* Ab = Xb + (size_t)c*MM*NN;
  const u16* Bb = Bt + (size_t)c*NN*NN;
  const int srow = lane>>2;                  // 0..15
  const int scol = ((lane&3) ^ (srow&3))*8;  // pre-swizzled source col (u16)
  const int fr = lane&15, c0 = lane>>4;      // frag row, k-chunk
  const int wm = (w>>2)*64, wn = (w&3)*64;   // wave tile origin in 256x256
  f4v acc[4][4] = {};
  auto STAGE = [&](int buf, int k0){
    // wave w stages A rows [w*16, w*16+16) and B rows [w*16, w*16+16)
    int arow = m0 + w*16 + srow;
    arow = arow < MM ? arow : MM-1;          // clamp OOB m-pad rows (not written)
    gload16(Ab + (size_t)arow*NN + k0 + scol,               (void*)&As[buf][(w*16)*32]);
    gload16(Bb + (size_t)(n0 + w*16 + srow)*NN + k0 + scol, (void*)&Bs[buf][(w*16)*32]);
  };
  STAGE(0, kb);
  __syncthreads();
  int cur = 0;
  for (int k0=0;k0<1024;k0+=32){
    if (k0+32 < 1024) STAGE(cur^1, kb+k0+32);   // next-tile loads fly under compute
    s8v a[4], b[4];
    #pragma unroll
    for (int t=0;t<4;t++){
      const int ra = wm + t*16 + fr;
      a[t] = *(const s8v*)&As[cur][ra*32 + ((c0 ^ (ra&3))*8)];
      const int rb2 = wn + t*16 + fr;
      b[t] = *(const s8v*)&Bs[cur][rb2*32 + ((c0 ^ (rb2&3))*8)];
    }
    #pragma unroll
    for (int i=0;i<4;i++)
      #pragma unroll
      for (int j=0;j<4;j++)
        acc[i][j] = __builtin_amdgcn_mfma_f32_16x16x32_bf16(a[i], b[j], acc[i][j], 0, 0, 0);
    __syncthreads();   // drains vmcnt: next buffer landed; cur reads done
    cur ^= 1;
  }
  float* pb = part + (size_t)(c*4+ks)*MM*NN;
  #pragma unroll
  for (int i=0;i<4;i++){
    #pragma unroll
    for (int j=0;j<4;j++){
      const int col = n0 + wn + j*16 + fr;
      #pragma unroll
      for (int rr=0;rr<4;rr++){
        const int row = m0 + wm + i*16 + (lane>>4)*4 + rr;
        if (row < MM) pb[(size_t)row*NN + col] = acc[i][j][rr];
      }
    }
  }
}

// Sum 4 K-split partials + epilogue -> bf16.
// M==1: u = (z - x*diag)*dinv.  M==2: e relu fusion (channel-0 differs).
template<int M>
__global__ __launch_bounds__(256)
void k_epi(const float* __restrict__ part, const float* __restrict__ seqs,
           const float* __restrict__ diag1, const float* __restrict__ dinv,
           const float* __restrict__ IB, u16* __restrict__ outp)
{
  const int g = blockIdx.x*256 + threadIdx.x;
  const int c = blockIdx.y;
  const int row = g>>10, col = (g&1023)*4;
  const size_t base = (size_t)row*NN + col;
  f4v z = {0.f,0.f,0.f,0.f};
  #pragma unroll
  for (int ks=0;ks<4;ks++)
    z += *(const f4v*)(part + (size_t)(c*4+ks)*MM*NN + base);
  f4v val;
  if constexpr(M==1){
    f4v x  = *(const f4v*)(seqs + base);
    f4v d  = *(const f4v*)(diag1 + (size_t)c*NN + col);
    f4v dv = *(const f4v*)(dinv  + (size_t)c*NN + col);
    val = (z - x*d) * dv;
  } else {
    f4v x  = *(const f4v*)(seqs + base);
    f4v ib = *(const f4v*)(IB + col);
    #pragma unroll
    for (int k=0;k<4;k++){
      float xh = fmaxf(z[k], 0.f);
      float vv = fmaxf(ib[k], 0.f);
      val[k] = (c==0) ? (fmaxf(x[k]*vv,0.f) + xh) : fmaxf(x[k]*vv + xh, 0.f);
    }
  }
  u2v o = { pkbf(val[0],val[1]), pkbf(val[2],val[3]) };
  *(u2v*)(outp + (size_t)c*MM*NN + base) = o;
}

// fp32 -> bf16 for lin_w (2*128*4096) and W_hh (512*128)
__global__ __launch_bounds__(256)
void k_cvt(const float* __restrict__ linw, const float* __restrict__ whh,
           u16* __restrict__ linwb, u16* __restrict__ whhb)
{
  const int g = blockIdx.x*256 + threadIdx.x;
  const int i = g*4;
  const int NL = 2*128*NN;
  f4v v; u16* dst;
  if (i < NL){ v = *(const f4v*)(linw + i); dst = linwb + i; }
  else       { v = *(const f4v*)(whh + (i-NL)); dst = whhb + (i-NL); }
  u2v o = { pkbf(v[0],v[1]), pkbf(v[2],v[3]) };
  *(u2v*)dst = o;
}

// enc_raw[row][c*128+d] += e[c] @ lin_w[c]^T  (K-split x16, atomic accumulate)
__global__ __launch_bounds__(256)
void k_lin(const u16* __restrict__ e, const u16* __restrict__ linwb,
           float* __restrict__ encr)
{
  __shared__ u16 As[64*32];
  __shared__ u16 Bs[64*32];
  const int tid=threadIdx.x, lane=tid&63, w=tid>>6;
  const int m0 = blockIdx.x*64, d0 = blockIdx.y*64;
  const int c = blockIdx.z>>4, ks = blockIdx.z&15;
  const u16* Ab = e + (size_t)c*MM*NN;
  const u16* Bb = linwb + (size_t)c*128*NN;
  const int srow=lane>>2, skof=(lane&3)*8, fr=lane&15, fk=(lane>>4)*8;
  const int wm=(w>>1)*32, wn=(w&1)*32;
  f4v acc[2][2];
  #pragma unroll
  for (int i=0;i<2;i++)
    #pragma unroll
    for (int j=0;j<2;j++) acc[i][j] = (f4v){0.f,0.f,0.f,0.f};
  for (int ki=0;ki<8;++ki){
    const int k0 = ks*256 + ki*32;
    gload16(Ab + (size_t)(m0 + w*16 + srow)*NN + k0 + skof, (void*)&As[(w*16)*32]);
    gload16(Bb + (size_t)(d0 + w*16 + srow)*NN + k0 + skof, (void*)&Bs[(w*16)*32]);
    __syncthreads();
    s8v a[2], b[2];
    #pragma unroll
    for (int t=0;t<2;t++) a[t] = *(const s8v*)&As[(wm+t*16+fr)*32+fk];
    #pragma unroll
    for (int t=0;t<2;t++) b[t] = *(const s8v*)&Bs[(wn+t*16+fr)*32+fk];
    #pragma unroll
    for (int i=0;i<2;i++)
      #pragma unroll
      for (int j=0;j<2;j++)
        acc[i][j] = __builtin_amdgcn_mfma_f32_16x16x32_bf16(a[i], b[j], acc[i][j], 0, 0, 0);
    __syncthreads();
  }
  #pragma unroll
  for (int i=0;i<2;i++)
    #pragma unroll
    for (int j=0;j<2;j++){
      const int col = d0 + wn + j*16 + fr;
      #pragma unroll
      for (int rr=0;rr<4;rr++){
        const int row = m0 + wm + i*16 + (lane>>4)*4 + rr;
        atomicAdd(&encr[(size_t)row*256 + c*128 + col], acc[i][j][rr]);
      }
    }
}

// baskets[row][d] = (enc+lin_b) @ proj_w^T + proj_b
__global__ __launch_bounds__(256)
void k_proj(const float* __restrict__ encr, const float* __restrict__ linb,
            const float* __restrict__ pw, const float* __restrict__ pb,
            float* __restrict__ bask)
{
  const int g = blockIdx.x*256 + threadIdx.x;
  const int row = g>>7, d = g&127;
  const float* er = encr + (size_t)row*256;
  const float* wr = pw + (size_t)d*256;
  float acc = pb[d];
  for (int j=0;j<256;j+=4){
    f4v e4 = *(const f4v*)(er+j);
    f4v l4 = *(const f4v*)(linb+j);
    f4v w4 = *(const f4v*)(wr+j);
    acc += (e4[0]+l4[0])*w4[0] + (e4[1]+l4[1])*w4[1] + (e4[2]+l4[2])*w4[2] + (e4[3]+l4[3])*w4[3];
  }
  bask[g] = acc;
}

// xhat[t][b][n] = baskets @ W_ih^T + b_ih + b_hh
__global__ __launch_bounds__(256)
void k_xhat(const float* __restrict__ bask, const float* __restrict__ wih,
            const float* __restrict__ bih, const float* __restrict__ bhh,
            float* __restrict__ xh)
{
  const int g = blockIdx.x*256 + threadIdx.x;
  const int row = g>>9, n = g&511;
  const float* br = bask + (size_t)row*128;
  const float* wr = wih + (size_t)n*128;
  float acc = bih[n] + bhh[n];
  for (int k=0;k<128;k+=4){
    f4v b4=*(const f4v*)(br+k); f4v w4=*(const f4v*)(wr+k);
    acc += b4[0]*w4[0]+b4[1]*w4[1]+b4[2]*w4[2]+b4[3]*w4[3];
  }
  const int b = row/20, t = row%20;
  xh[((size_t)t*32 + b)*512 + n] = acc;
}

// single-block LSTM, 8 waves; W_hh B-frags live in registers across the 20 steps
__global__ __launch_bounds__(512)
void k_lstm(const float* __restrict__ xhat, const u16* __restrict__ whhb,
            const float* __restrict__ h0, const float* __restrict__ c0,
            const int* __restrict__ slen, float* __restrict__ last)
{
  __shared__ float zb[32][512];
  __shared__ float cbuf[32][128];
  __shared__ u16 hb[32][136];
  const int tid = threadIdx.x, lane = tid&63, w = tid>>6;
  for (int i=tid; i<4096; i+=512){ int b=i>>7,u=i&127; cbuf[b][u]=c0[i]; hb[b][u]=f2bf(h0[i]); }
  const int fr = lane&15, fko = (lane>>4)*8;
  s8v bfr[4][4];
  #pragma unroll
  for (int nt=0;nt<4;nt++)
    #pragma unroll
    for (int kf=0;kf<4;kf++)
      bfr[nt][kf] = *(const s8v*)(whhb + (size_t)(w*64 + nt*16 + fr)*128 + kf*32 + fko);
  __syncthreads();
  for (int t=0;t<20;++t){
    s8v af[2][4];
    #pragma unroll
    for (int mt=0;mt<2;mt++)
      #pragma unroll
      for (int kf=0;kf<4;kf++)
        af[mt][kf] = *(const s8v*)&hb[mt*16+fr][kf*32+fko];
    f4v z[2][4];
    #pragma unroll
    for (int mt=0;mt<2;mt++)
      #pragma unroll
      for (int nt=0;nt<4;nt++){
        const int nn2 = w*64 + nt*16 + fr;
        #pragma unroll
        for (int rr=0;rr<4;rr++){
          const int bb = mt*16 + (lane>>4)*4 + rr;
          z[mt][nt][rr] = xhat[((size_t)t*32 + bb)*512 + nn2];
        }
      }
    #pragma unroll
    for (int kf=0;kf<4;kf++)
      #pragma unroll
      for (int mt=0;mt<2;mt++)
        #pragma unroll
        for (int nt=0;nt<4;nt++)
          z[mt][nt] = __builtin_amdgcn_mfma_f32_16x16x32_bf16(af[mt][kf], bfr[nt][kf], z[mt][nt], 0, 0, 0);
    #pragma unroll
    for (int mt=0;mt<2;mt++)
      #pragma unroll
      for (int nt=0;nt<4;nt++){
        const int nn2 = w*64 + nt*16 + fr;
        #pragma unroll
        for (int rr=0;rr<4;rr++){
          const int bb = mt*16 + (lane>>4)*4 + rr;
          zb[bb][nn2] = z[mt][nt][rr];
        }
      }
    __syncthreads();
    for (int p=tid; p<4096; p+=512){
      const int b=p>>7, u=p&127;
      float zi=zb[b][u], zf=zb[b][128+u], zg=zb[b][256+u], zo=zb[b][384+u];
      float ii=sigm(zi), ff=sigm(zf), gg=tanhf(zg), oo=sigm(zo);
      float cn = ff*cbuf[b][u] + ii*gg;
      float hn = oo*tanhf(cn);
      cbuf[b][u]=cn; hb[b][u]=f2bf(hn);
      if (t == slen[b]-1) last[p] = hn;
    }
    __syncthreads();
  }
}

// out[b][n] = sigmoid(last[b].h2w[n]) * ((1-a) + a*relu(I_B[n]))
__global__ __launch_bounds__(256)
void k_final(const float* __restrict__ last, const float* __restrict__ h2w,
             const float* __restrict__ IB, float* __restrict__ out)
{
  __shared__ float ls[128];
  const int b = blockIdx.y;
  const int n = blockIdx.x*256 + threadIdx.x;
  if (threadIdx.x < 128) ls[threadIdx.x] = last[b*128 + threadIdx.x];
  __syncthreads();
  const float* wr = h2w + (size_t)n*128;
  float acc = 0.f;
  for (int k=0;k<128;k+=4){
    f4v w4 = *(const f4v*)(wr+k);
    acc += w4[0]*ls[k] + w4[1]*ls[k+1] + w4[2]*ls[k+2] + w4[3]*ls[k+3];
  }
  const float vn = fmaxf(IB[n], 0.f);
  out[(size_t)b*NN + n] = (0.5f + 0.5f*vn) * sigm(acc);
}

extern "C" void kernel_launch(void* const* d_in, const int* in_sizes, int n_in,
                              void* d_out, int out_size, void* d_ws, size_t ws_size,
                              hipStream_t stream)
{
  const float* A    = (const float*)d_in[0];
  const float* seqs = (const float*)d_in[1];
  const int*   slen = (const int*)  d_in[2];
  const float* h0   = (const float*)d_in[3];
  const float* c0   = (const float*)d_in[4];
  const float* W1a  = (const float*)d_in[5];
  const float* W1b  = (const float*)d_in[6];
  const float* W2   = (const float*)d_in[7];
  const float* IB   = (const float*)d_in[8];
  const float* linw = (const float*)d_in[9];
  const float* linb = (const float*)d_in[10];
  const float* pw   = (const float*)d_in[11];
  const float* pb   = (const float*)d_in[12];
  const float* wih  = (const float*)d_in[13];
  const float* whh  = (const float*)d_in[14];
  const float* bih  = (const float*)d_in[15];
  const float* bhh  = (const float*)d_in[16];
  const float* h2w  = (const float*)d_in[17];
  (void)in_sizes; (void)n_in; (void)out_size; (void)ws_size;

  char* ws = (char*)d_ws;
  size_t off = 0;
  auto alloc = [&](size_t sz)->void*{ void* p = ws + off; off += (sz + 255) & ~(size_t)255; return p; };
  u16*   C1    = (u16*)  alloc((size_t)2*NN*NN*2);
  u16*   C2t   = (u16*)  alloc((size_t)2*NN*NN*2);
  u16*   C3t   = (u16*)  alloc((size_t)2*NN*NN*2);
  u16*   y     = (u16*)  alloc((size_t)2*MM*NN*2);   // reused as e
  u16*   u     = (u16*)  alloc((size_t)2*MM*NN*2);
  float* part  = (float*)alloc((size_t)4*2*MM*NN*4); // 84 MB fp32 partials
  float* r     = (float*)alloc((size_t)2*NN*4);
  float* diag1 = (float*)alloc((size_t)2*NN*4);
  float* dinv  = (float*)alloc((size_t)2*NN*4);
  u16*   linwb = (u16*)  alloc((size_t)2*128*NN*2);
  u16*   whhb  = (u16*)  alloc((size_t)512*128*2);
  float* encr  = (float*)alloc((size_t)MM*256*4);
  float* bask  = (float*)alloc((size_t)MM*128*4);
  float* xh    = (float*)alloc((size_t)20*32*512*4);
  float* last  = (float*)alloc((size_t)32*128*4);
  // total ~300 MB

  hipMemsetAsync(r, 0, (size_t)2*NN*4, stream);       // atomically accumulated
  hipMemsetAsync(encr, 0, (size_t)MM*256*4, stream);

  k_combine_all<<<dim3(64,64),256,0,stream>>>(A, W1a, W1b, W2, C1, C2t, C3t, r);
  k_sparse_y<<<MM,256,0,stream>>>(seqs, C1, y);
  k_diagdeg<<<2048,256,0,stream>>>(C1, C2t, r, diag1, dinv);
  k_gemm_sk<<<384,1024,0,stream>>>(y, C2t, part);               // G2: y @ C2
  k_epi<1><<<dim3(2560,2),256,0,stream>>>(part, seqs, diag1, dinv, IB, u);
  k_gemm_sk<<<384,1024,0,stream>>>(u, C3t, part);               // G3: u @ C3
  u16* e = y;                                                   // y dead, alias as e
  k_epi<2><<<dim3(2560,2),256,0,stream>>>(part, seqs, diag1, dinv, IB, e);
  k_cvt<<<1088,256,0,stream>>>(linw, whh, linwb, whhb);
  k_lin<<<dim3(10,2,32),256,0,stream>>>(e, linwb, encr);
  k_proj<<<320,256,0,stream>>>(encr, linb, pw, pb, bask);
  k_xhat<<<1280,256,0,stream>>>(bask, wih, bih, bhh, xh);
  k_lstm<<<1,512,0,stream>>>(xh, whhb, h0, c0, slen, last);
  k_final<<<dim3(16,32),256,0,stream>>>(last, h2w, IB, (float*)d_out);
}

// Round 11
// 530.745 us; speedup vs baseline: 1.0620x; 1.0491x over previous
//
#include <hip/hip_runtime.h>

// GTN forward, restructured: never materialize H = conv1@conv2 (4096x4096).
// x@H1 = (x@C1)@C2 ; normalize needs only diag(H1) and colsum(H1)=r@C2.
// R11: revert gemm to R8 form (best measured). sparse_y: ORDERED index list
// via block-wide exclusive scan (was atomicAdd-permuted) -> all co-resident
// blocks sweep C1 rows in ascending-j lockstep -> L3 temporal locality
// (unique set 64MB << 256MB L3; R7-R10 measured 360MB FETCH = 5.6x overfetch
// from random-order gathers).

typedef float  f4v  __attribute__((ext_vector_type(4)));
typedef short  s8v  __attribute__((ext_vector_type(8)));
typedef unsigned short u16;
typedef unsigned int u32;
typedef u32    u2v  __attribute__((ext_vector_type(2)));
typedef u32    u4v  __attribute__((ext_vector_type(4)));

#define NN 4096
#define MM 640   // B*L

__device__ __forceinline__ u16 f2bf(float f){
  unsigned int u = __float_as_uint(f);
  u += 0x7FFFu + ((u>>16)&1u);
  return (u16)(u>>16);
}
__device__ __forceinline__ float bf2f(u16 h){ return __uint_as_float(((unsigned int)h)<<16); }
__device__ __forceinline__ float sigm(float x){ return 1.f/(1.f+__expf(-x)); }

// packed f32x2 -> bf16x2 (RNE), single VALU inst on gfx950
__device__ __forceinline__ u32 pkbf(float lo, float hi){
  u32 r;
  asm("v_cvt_pk_bf16_f32 %0, %1, %2" : "=v"(r) : "v"(lo), "v"(hi));
  return r;
}

__device__ __forceinline__ void gload16(const void* g, void* l){
  __builtin_amdgcn_global_load_lds((const __attribute__((address_space(1))) unsigned int*)g,
                                   (__attribute__((address_space(3))) unsigned int*)l, 16, 0, 0);
}

__device__ __forceinline__ void softmax23(const float* __restrict__ W, float f[2][3]){
  #pragma unroll
  for (int c=0;c<2;c++){
    float a=W[c*3+0], b=W[c*3+1], d=W[c*3+2];
    float m=fmaxf(a,fmaxf(b,d));
    float ea=__expf(a-m), eb=__expf(b-m), ed=__expf(d-m);
    float s=1.f/(ea+eb+ed);
    f[c][0]=ea*s; f[c][1]=eb*s; f[c][2]=ed*s;
  }
}

// Read A once; produce C1 (straight bf16), C2t/C3t (transposed bf16), r=colsum(C1).
__global__ __launch_bounds__(256)
void k_combine_all(const float* __restrict__ A, const float* __restrict__ W1a,
                   const float* __restrict__ W1b, const float* __restrict__ W2,
                   u16* __restrict__ C1, u16* __restrict__ C2t,
                   u16* __restrict__ C3t, float* __restrict__ r)
{
  __shared__ u16 t2[64][72];
  __shared__ u16 t3[64][72];
  __shared__ float rs[2][64];
  const int tid = threadIdx.x, lane = tid&63;
  const int n0 = blockIdx.x*64, m0 = blockIdx.y*64;
  float fa[2][3], fb[2][3], fc[2][3];
  softmax23(W1a, fa); softmax23(W1b, fb); softmax23(W2, fc);
  if (tid < 128) rs[tid>>6][tid&63] = 0.f;
  const int mb = tid>>4, nb = tid&15;
  f4v a0[4], a1[4], a2[4];
  #pragma unroll
  for (int j=0;j<4;j++){
    const float* ap = A + (size_t)(m0+mb*4+j)*NN + n0 + nb*4;
    a0[j] = *(const f4v*)ap;
    a1[j] = *(const f4v*)(ap + (size_t)NN*NN);
    a2[j] = *(const f4v*)(ap + 2*(size_t)NN*NN);
  }
  #pragma unroll
  for (int c=0;c<2;c++){
    float rp[4] = {};
    #pragma unroll
    for (int j=0;j<4;j++){
      f4v v1 = fa[c][0]*a0[j] + fa[c][1]*a1[j] + fa[c][2]*a2[j];
      u2v o = { pkbf(v1[0],v1[1]), pkbf(v1[2],v1[3]) };
      *(u2v*)(C1 + ((size_t)c*NN + m0+mb*4+j)*NN + n0 + nb*4) = o;
      #pragma unroll
      for (int k=0;k<4;k++) rp[k] += v1[k];
    }
    #pragma unroll
    for (int jj=0;jj<4;jj++){
      f4v c2v, c3v;
      #pragma unroll
      for (int j=0;j<4;j++){
        c2v[j] = fb[c][0]*a0[j][jj] + fb[c][1]*a1[j][jj] + fb[c][2]*a2[j][jj];
        c3v[j] = fc[c][0]*a0[j][jj] + fc[c][1]*a1[j][jj] + fc[c][2]*a2[j][jj];
      }
      *(u2v*)&t2[nb*4+jj][mb*4] = (u2v){ pkbf(c2v[0],c2v[1]), pkbf(c2v[2],c2v[3]) };
      *(u2v*)&t3[nb*4+jj][mb*4] = (u2v){ pkbf(c3v[0],c3v[1]), pkbf(c3v[2],c3v[3]) };
    }
    __syncthreads();
    #pragma unroll
    for (int rep=0;rep<2;rep++){
      const int rw = rep*32 + (tid>>3), l8 = tid&7;
      *(u4v*)(C2t + ((size_t)c*NN + n0+rw)*NN + m0 + l8*8) = *(const u4v*)&t2[rw][l8*8];
      *(u4v*)(C3t + ((size_t)c*NN + n0+rw)*NN + m0 + l8*8) = *(const u4v*)&t3[rw][l8*8];
    }
    #pragma unroll
    for (int k=0;k<4;k++){
      float v = rp[k];
      v += __shfl_xor(v,16); v += __shfl_xor(v,32);
      if (lane < 16) atomicAdd(&rs[c][nb*4+k], v);
    }
    __syncthreads();
  }
  if (tid < 128) atomicAdd(&r[(size_t)(tid>>6)*NN + n0 + (tid&63)], rs[tid>>6][tid&63]);
}

// y[c][row][:] = sum over nnz(x[row]) of C1[c][j][:]  (x binary, ~2% dense)
// ORDERED index list (block-wide exclusive scan) -> ascending-j gather sweep
// -> co-resident blocks share the L3 window. 16 cols/thread/channel,
// 1-ahead prefetch.
__global__ __launch_bounds__(256)
void k_sparse_y(const float* __restrict__ seqs, const u16* __restrict__ C1,
                u16* __restrict__ y)
{
  __shared__ int idxl[512];
  __shared__ int scan[256];
  const int tid = threadIdx.x, row = blockIdx.x;
  const float* xr = seqs + (size_t)row*NN;
  int runbase = 0;
  #pragma unroll
  for (int it=0; it<4; ++it){
    f4v v = *(const f4v*)(xr + it*1024 + tid*4);
    int flg[4], loc = 0;
    #pragma unroll
    for (int k=0;k<4;k++){ flg[k] = (v[k] > 0.5f); loc += flg[k]; }
    scan[tid] = loc;
    __syncthreads();
    #pragma unroll
    for (int off=1; off<256; off<<=1){
      int t = (tid>=off) ? scan[tid-off] : 0;
      __syncthreads();
      scan[tid] += t;
      __syncthreads();
    }
    int pos = runbase + scan[tid] - loc;
    #pragma unroll
    for (int k=0;k<4;k++)
      if (flg[k]){ if (pos < 512) idxl[pos] = it*1024 + tid*4 + k; pos++; }
    runbase += scan[255];
    __syncthreads();
  }
  const int nz = runbase < 512 ? runbase : 512;
  float acc0[16], acc1[16];
  #pragma unroll
  for (int k=0;k<16;k++){ acc0[k]=0.f; acc1[k]=0.f; }
  const int cb = tid*16;
  s8v ca, cb8, cc8, cd8;
  if (nz > 0){
    const u16* r0 = C1 + (size_t)idxl[0]*NN + cb;
    const u16* r1 = r0 + (size_t)NN*NN;
    ca=*(const s8v*)r0; cb8=*(const s8v*)(r0+8); cc8=*(const s8v*)r1; cd8=*(const s8v*)(r1+8);
  }
  for (int p=0;p<nz;++p){
    const int pn = (p+1<nz)? p+1 : p;
    const u16* r0 = C1 + (size_t)idxl[pn]*NN + cb;
    const u16* r1 = r0 + (size_t)NN*NN;
    s8v na=*(const s8v*)r0, nb=*(const s8v*)(r0+8), nc=*(const s8v*)r1, nd=*(const s8v*)(r1+8);
    #pragma unroll
    for (int k=0;k<8;k++){
      acc0[k]   += bf2f((u16)ca[k]);
      acc0[8+k] += bf2f((u16)cb8[k]);
      acc1[k]   += bf2f((u16)cc8[k]);
      acc1[8+k] += bf2f((u16)cd8[k]);
    }
    ca=na; cb8=nb; cc8=nc; cd8=nd;
  }
  u4v o0, o1;
  #pragma unroll
  for (int k=0;k<4;k++){
    o0[k] = pkbf(acc0[2*k], acc0[2*k+1]);
    o1[k] = pkbf(acc0[8+2*k], acc0[9+2*k]);
  }
  u16* y0 = y + (size_t)row*NN + cb;
  *(u4v*)y0 = o0; *(u4v*)(y0+8) = o1;
  #pragma unroll
  for (int k=0;k<4;k++){
    o0[k] = pkbf(acc1[2*k], acc1[2*k+1]);
    o1[k] = pkbf(acc1[8+2*k], acc1[9+2*k]);
  }
  u16* y1 = y0 + (size_t)MM*NN;
  *(u4v*)y1 = o0; *(u4v*)(y1+8) = o1;
}

// diag1[c][k] = dot(C1[c][k][:], C2t[c][k][:]) ; deg = dot(r[c], C2t[c][k][:]) - diag
__global__ __launch_bounds__(256)
void k_diagdeg(const u16* __restrict__ C1, const u16* __restrict__ C2t,
               const float* __restrict__ r, float* __restrict__ diag1,
               float* __restrict__ dinv)
{
  const int tid = threadIdx.x, lane = tid&63;
  const int gw = blockIdx.x*4 + (tid>>6);
  const int c = gw>>12, k = gw&4095;
  const u16* p1 = C1  + ((size_t)c*NN + k)*NN;
  const u16* p2 = C2t + ((size_t)c*NN + k)*NN;
  const float* pr = r + (size_t)c*NN;
  float dd = 0.f, dg = 0.f;
  for (int it=0; it<8; ++it){
    const int j = it*512 + lane*8;
    s8v v1 = *(const s8v*)(p1+j);
    s8v v2 = *(const s8v*)(p2+j);
    f4v r0 = *(const f4v*)(pr+j);
    f4v r1 = *(const f4v*)(pr+j+4);
    #pragma unroll
    for (int q=0;q<8;q++){
      float c2 = bf2f((u16)v2[q]);
      dd += bf2f((u16)v1[q]) * c2;
      dg += ((q<4)? r0[q] : r1[q-4]) * c2;
    }
  }
  #pragma unroll
  for (int m=1;m<64;m<<=1){ dd += __shfl_xor(dd, m); dg += __shfl_xor(dg, m); }
  if (lane==0){
    float deg = dg - dd;
    diag1[(size_t)c*NN+k] = dd;
    dinv[(size_t)c*NN+k]  = (deg==0.f) ? 0.f : 1.f/deg;
  }
}

// Split-K GEMM (R8 form, best measured): part[c*4+ks] = Xb[c][:, ks*1024:+1024] @ Bt[c][:, same]^T
// 128x128 tile, BK=32, 4 waves, double-buffered LDS, STAGE(next) before
// compute, one __syncthreads per K-step. Grid 1280 flat, XCD decode
// (n%8 == g%8), swizzled LDS (rule #21 pair).
__global__ __launch_bounds__(256)
void k_gemm_sk(const u16* __restrict__ Xb, const u16* __restrict__ Bt,
               float* __restrict__ part)
{
  __shared__ u16 As[2][128*32];
  __shared__ u16 Bs[2][128*32];
  const int tid = threadIdx.x, lane = tid&63, w = tid>>6;
  const int g = blockIdx.x;
  const int xcd = g & 7, q = g >> 3;        // q in [0,160)
  const int m = q % 5, p = q / 5;           // p in [0,32)
  const int nh = p & 3, ks = (p>>2)&3, c = (p>>4)&1;
  const int m0 = m*128, n0 = (nh*8 + xcd)*128, kb = ks*1024;
  const u16* Ab = Xb + (size_t)c*MM*NN;
  const u16* Bb = Bt + (size_t)c*NN*NN;
  const int srow = lane>>2;                  // 0..15
  const int scol = ((lane&3) ^ (srow&3))*8;  // pre-swizzled source col (u16)
  const int fr = lane&15, c0 = lane>>4;      // frag row, k-chunk
  const int wm = (w>>1)*64, wn = (w&1)*64;
  f4v acc[4][4] = {};
  auto STAGE = [&](int buf, int k0){
    #pragma unroll
    for (int i=0;i<2;i++){
      const int rb = i*64 + w*16;
      gload16(Ab + (size_t)(m0 + rb + srow)*NN + k0 + scol, (void*)&As[buf][rb*32]);
      gload16(Bb + (size_t)(n0 + rb + srow)*NN + k0 + scol, (void*)&Bs[buf][rb*32]);
    }
  };
  STAGE(0, kb);
  __syncthreads();
  int cur = 0;
  for (int k0=0;k0<1024;k0+=32){
    if (k0+32 < 1024) STAGE(cur^1, kb+k0+32);   // loads fly under ds_read+MFMA
    s8v a[4], b[4];
    #pragma unroll
    for (int t=0;t<4;t++){
      const int ra = wm + t*16 + fr;
      a[t] = *(const s8v*)&As[cur][ra*32 + ((c0 ^ (ra&3))*8)];
      const int rb2 = wn + t*16 + fr;
      b[t] = *(const s8v*)&Bs[cur][rb2*32 + ((c0 ^ (rb2&3))*8)];
    }
    #pragma unroll
    for (int i=0;i<4;i++)
      #pragma unroll
      for (int j=0;j<4;j++)
        acc[i][j] = __builtin_amdgcn_mfma_f32_16x16x32_bf16(a[i], b[j], acc[i][j], 0, 0, 0);
    __syncthreads();   // next-tile loads landed; cur buffer's reads done
    cur ^= 1;
  }
  float* pb = part + (size_t)(c*4+ks)*MM*NN;
  #pragma unroll
  for (int i=0;i<4;i++){
    #pragma unroll
    for (int j=0;j<4;j++){
      const int col = n0 + wn + j*16 + fr;
      #pragma unroll
      for (int rr=0;rr<4;rr++){
        const int row = m0 + wm + i*16 + (lane>>4)*4 + rr;
        pb[(size_t)row*NN + col] = acc[i][j][rr];
      }
    }
  }
}

// Sum 4 K-split partials + epilogue -> bf16.
// M==1: u = (z - x*diag)*dinv.  M==2: e relu fusion (channel-0 differs).
template<int M>
__global__ __launch_bounds__(256)
void k_epi(const float* __restrict__ part, const float* __restrict__ seqs,
           const float* __restrict__ diag1, const float* __restrict__ dinv,
           const float* __restrict__ IB, u16* __restrict__ outp)
{
  const int g = blockIdx.x*256 + threadIdx.x;
  const int c = blockIdx.y;
  const int row = g>>10, col = (g&1023)*4;
  const size_t base = (size_t)row*NN + col;
  f4v z = {0.f,0.f,0.f,0.f};
  #pragma unroll
  for (int ks=0;ks<4;ks++)
    z += *(const f4v*)(part + (size_t)(c*4+ks)*MM*NN + base);
  f4v val;
  if constexpr(M==1){
    f4v x  = *(const f4v*)(seqs + base);
    f4v d  = *(const f4v*)(diag1 + (size_t)c*NN + col);
    f4v dv = *(const f4v*)(dinv  + (size_t)c*NN + col);
    val = (z - x*d) * dv;
  } else {
    f4v x  = *(const f4v*)(seqs + base);
    f4v ib = *(const f4v*)(IB + col);
    #pragma unroll
    for (int k=0;k<4;k++){
      float xh = fmaxf(z[k], 0.f);
      float vv = fmaxf(ib[k], 0.f);
      val[k] = (c==0) ? (fmaxf(x[k]*vv,0.f) + xh) : fmaxf(x[k]*vv + xh, 0.f);
    }
  }
  u2v o = { pkbf(val[0],val[1]), pkbf(val[2],val[3]) };
  *(u2v*)(outp + (size_t)c*MM*NN + base) = o;
}

// fp32 -> bf16 for lin_w (2*128*4096) and W_hh (512*128)
__global__ __launch_bounds__(256)
void k_cvt(const float* __restrict__ linw, const float* __restrict__ whh,
           u16* __restrict__ linwb, u16* __restrict__ whhb)
{
  const int g = blockIdx.x*256 + threadIdx.x;
  const int i = g*4;
  const int NL = 2*128*NN;
  f4v v; u16* dst;
  if (i < NL){ v = *(const f4v*)(linw + i); dst = linwb + i; }
  else       { v = *(const f4v*)(whh + (i-NL)); dst = whhb + (i-NL); }
  u2v o = { pkbf(v[0],v[1]), pkbf(v[2],v[3]) };
  *(u2v*)dst = o;
}

// enc_raw[row][c*128+d] += e[c] @ lin_w[c]^T  (K-split x16, atomic accumulate)
__global__ __launch_bounds__(256)
void k_lin(const u16* __restrict__ e, const u16* __restrict__ linwb,
           float* __restrict__ encr)
{
  __shared__ u16 As[64*32];
  __shared__ u16 Bs[64*32];
  const int tid=threadIdx.x, lane=tid&63, w=tid>>6;
  const int m0 = blockIdx.x*64, d0 = blockIdx.y*64;
  const int c = blockIdx.z>>4, ks = blockIdx.z&15;
  const u16* Ab = e + (size_t)c*MM*NN;
  const u16* Bb = linwb + (size_t)c*128*NN;
  const int srow=lane>>2, skof=(lane&3)*8, fr=lane&15, fk=(lane>>4)*8;
  const int wm=(w>>1)*32, wn=(w&1)*32;
  f4v acc[2][2];
  #pragma unroll
  for (int i=0;i<2;i++)
    #pragma unroll
    for (int j=0;j<2;j++) acc[i][j] = (f4v){0.f,0.f,0.f,0.f};
  for (int ki=0;ki<8;++ki){
    const int k0 = ks*256 + ki*32;
    gload16(Ab + (size_t)(m0 + w*16 + srow)*NN + k0 + skof, (void*)&As[(w*16)*32]);
    gload16(Bb + (size_t)(d0 + w*16 + srow)*NN + k0 + skof, (void*)&Bs[(w*16)*32]);
    __syncthreads();
    s8v a[2], b[2];
    #pragma unroll
    for (int t=0;t<2;t++) a[t] = *(const s8v*)&As[(wm+t*16+fr)*32+fk];
    #pragma unroll
    for (int t=0;t<2;t++) b[t] = *(const s8v*)&Bs[(wn+t*16+fr)*32+fk];
    #pragma unroll
    for (int i=0;i<2;i++)
      #pragma unroll
      for (int j=0;j<2;j++)
        acc[i][j] = __builtin_amdgcn_mfma_f32_16x16x32_bf16(a[i], b[j], acc[i][j], 0, 0, 0);
    __syncthreads();
  }
  #pragma unroll
  for (int i=0;i<2;i++)
    #pragma unroll
    for (int j=0;j<2;j++){
      const int col = d0 + wn + j*16 + fr;
      #pragma unroll
      for (int rr=0;rr<4;rr++){
        const int row = m0 + wm + i*16 + (lane>>4)*4 + rr;
        atomicAdd(&encr[(size_t)row*256 + c*128 + col], acc[i][j][rr]);
      }
    }
}

// baskets[row][d] = (enc+lin_b) @ proj_w^T + proj_b
__global__ __launch_bounds__(256)
void k_proj(const float* __restrict__ encr, const float* __restrict__ linb,
            const float* __restrict__ pw, const float* __restrict__ pb,
            float* __restrict__ bask)
{
  const int g = blockIdx.x*256 + threadIdx.x;
  const int row = g>>7, d = g&127;
  const float* er = encr + (size_t)row*256;
  const float* wr = pw + (size_t)d*256;
  float acc = pb[d];
  for (int j=0;j<256;j+=4){
    f4v e4 = *(const f4v*)(er+j);
    f4v l4 = *(const f4v*)(linb+j);
    f4v w4 = *(const f4v*)(wr+j);
    acc += (e4[0]+l4[0])*w4[0] + (e4[1]+l4[1])*w4[1] + (e4[2]+l4[2])*w4[2] + (e4[3]+l4[3])*w4[3];
  }
  bask[g] = acc;
}

// xhat[t][b][n] = baskets @ W_ih^T + b_ih + b_hh
__global__ __launch_bounds__(256)
void k_xhat(const float* __restrict__ bask, const float* __restrict__ wih,
            const float* __restrict__ bih, const float* __restrict__ bhh,
            float* __restrict__ xh)
{
  const int g = blockIdx.x*256 + threadIdx.x;
  const int row = g>>9, n = g&511;
  const float* br = bask + (size_t)row*128;
  const float* wr = wih + (size_t)n*128;
  float acc = bih[n] + bhh[n];
  for (int k=0;k<128;k+=4){
    f4v b4=*(const f4v*)(br+k); f4v w4=*(const f4v*)(wr+k);
    acc += b4[0]*w4[0]+b4[1]*w4[1]+b4[2]*w4[2]+b4[3]*w4[3];
  }
  const int b = row/20, t = row%20;
  xh[((size_t)t*32 + b)*512 + n] = acc;
}

// single-block LSTM, 8 waves; W_hh B-frags live in registers across the 20 steps
__global__ __launch_bounds__(512)
void k_lstm(const float* __restrict__ xhat, const u16* __restrict__ whhb,
            const float* __restrict__ h0, const float* __restrict__ c0,
            const int* __restrict__ slen, float* __restrict__ last)
{
  __shared__ float zb[32][512];
  __shared__ float cbuf[32][128];
  __shared__ u16 hb[32][136];
  const int tid = threadIdx.x, lane = tid&63, w = tid>>6;
  for (int i=tid; i<4096; i+=512){ int b=i>>7,u=i&127; cbuf[b][u]=c0[i]; hb[b][u]=f2bf(h0[i]); }
  const int fr = lane&15, fko = (lane>>4)*8;
  s8v bfr[4][4];
  #pragma unroll
  for (int nt=0;nt<4;nt++)
    #pragma unroll
    for (int kf=0;kf<4;kf++)
      bfr[nt][kf] = *(const s8v*)(whhb + (size_t)(w*64 + nt*16 + fr)*128 + kf*32 + fko);
  __syncthreads();
  for (int t=0;t<20;++t){
    s8v af[2][4];
    #pragma unroll
    for (int mt=0;mt<2;mt++)
      #pragma unroll
      for (int kf=0;kf<4;kf++)
        af[mt][kf] = *(const s8v*)&hb[mt*16+fr][kf*32+fko];
    f4v z[2][4];
    #pragma unroll
    for (int mt=0;mt<2;mt++)
      #pragma unroll
      for (int nt=0;nt<4;nt++){
        const int nn2 = w*64 + nt*16 + fr;
        #pragma unroll
        for (int rr=0;rr<4;rr++){
          const int bb = mt*16 + (lane>>4)*4 + rr;
          z[mt][nt][rr] = xhat[((size_t)t*32 + bb)*512 + nn2];
        }
      }
    #pragma unroll
    for (int kf=0;kf<4;kf++)
      #pragma unroll
      for (int mt=0;mt<2;mt++)
        #pragma unroll
        for (int nt=0;nt<4;nt++)
          z[mt][nt] = __builtin_amdgcn_mfma_f32_16x16x32_bf16(af[mt][kf], bfr[nt][kf], z[mt][nt], 0, 0, 0);
    #pragma unroll
    for (int mt=0;mt<2;mt++)
      #pragma unroll
      for (int nt=0;nt<4;nt++){
        const int nn2 = w*64 + nt*16 + fr;
        #pragma unroll
        for (int rr=0;rr<4;rr++){
          const int bb = mt*16 + (lane>>4)*4 + rr;
          zb[bb][nn2] = z[mt][nt][rr];
        }
      }
    __syncthreads();
    for (int p=tid; p<4096; p+=512){
      const int b=p>>7, u=p&127;
      float zi=zb[b][u], zf=zb[b][128+u], zg=zb[b][256+u], zo=zb[b][384+u];
      float ii=sigm(zi), ff=sigm(zf), gg=tanhf(zg), oo=sigm(zo);
      float cn = ff*cbuf[b][u] + ii*gg;
      float hn = oo*tanhf(cn);
      cbuf[b][u]=cn; hb[b][u]=f2bf(hn);
      if (t == slen[b]-1) last[p] = hn;
    }
    __syncthreads();
  }
}

// out[b][n] = sigmoid(last[b].h2w[n]) * ((1-a) + a*relu(I_B[n]))
__global__ __launch_bounds__(256)
void k_final(const float* __restrict__ last, const float* __restrict__ h2w,
             const float* __restrict__ IB, float* __restrict__ out)
{
  __shared__ float ls[128];
  const int b = blockIdx.y;
  const int n = blockIdx.x*256 + threadIdx.x;
  if (threadIdx.x < 128) ls[threadIdx.x] = last[b*128 + threadIdx.x];
  __syncthreads();
  const float* wr = h2w + (size_t)n*128;
  float acc = 0.f;
  for (int k=0;k<128;k+=4){
    f4v w4 = *(const f4v*)(wr+k);
    acc += w4[0]*ls[k] + w4[1]*ls[k+1] + w4[2]*ls[k+2] + w4[3]*ls[k+3];
  }
  const float vn = fmaxf(IB[n], 0.f);
  out[(size_t)b*NN + n] = (0.5f + 0.5f*vn) * sigm(acc);
}

extern "C" void kernel_launch(void* const* d_in, const int* in_sizes, int n_in,
                              void* d_out, int out_size, void* d_ws, size_t ws_size,
                              hipStream_t stream)
{
  const float* A    = (const float*)d_in[0];
  const float* seqs = (const float*)d_in[1];
  const int*   slen = (const int*)  d_in[2];
  const float* h0   = (const float*)d_in[3];
  const float* c0   = (const float*)d_in[4];
  const float* W1a  = (const float*)d_in[5];
  const float* W1b  = (const float*)d_in[6];
  const float* W2   = (const float*)d_in[7];
  const float* IB   = (const float*)d_in[8];
  const float* linw = (const float*)d_in[9];
  const float* linb = (const float*)d_in[10];
  const float* pw   = (const float*)d_in[11];
  const float* pb   = (const float*)d_in[12];
  const float* wih  = (const float*)d_in[13];
  const float* whh  = (const float*)d_in[14];
  const float* bih  = (const float*)d_in[15];
  const float* bhh  = (const float*)d_in[16];
  const float* h2w  = (const float*)d_in[17];
  (void)in_sizes; (void)n_in; (void)out_size; (void)ws_size;

  char* ws = (char*)d_ws;
  size_t off = 0;
  auto alloc = [&](size_t sz)->void*{ void* p = ws + off; off += (sz + 255) & ~(size_t)255; return p; };
  u16*   C1    = (u16*)  alloc((size_t)2*NN*NN*2);
  u16*   C2t   = (u16*)  alloc((size_t)2*NN*NN*2);
  u16*   C3t   = (u16*)  alloc((size_t)2*NN*NN*2);
  u16*   y     = (u16*)  alloc((size_t)2*MM*NN*2);   // reused as e
  u16*   u     = (u16*)  alloc((size_t)2*MM*NN*2);
  float* part  = (float*)alloc((size_t)4*2*MM*NN*4); // 84 MB fp32 partials
  float* r     = (float*)alloc((size_t)2*NN*4);
  float* diag1 = (float*)alloc((size_t)2*NN*4);
  float* dinv  = (float*)alloc((size_t)2*NN*4);
  u16*   linwb = (u16*)  alloc((size_t)2*128*NN*2);
  u16*   whhb  = (u16*)  alloc((size_t)512*128*2);
  float* encr  = (float*)alloc((size_t)MM*256*4);
  float* bask  = (float*)alloc((size_t)MM*128*4);
  float* xh    = (float*)alloc((size_t)20*32*512*4);
  float* last  = (float*)alloc((size_t)32*128*4);
  // total ~300 MB

  hipMemsetAsync(r, 0, (size_t)2*NN*4, stream);       // atomically accumulated
  hipMemsetAsync(encr, 0, (size_t)MM*256*4, stream);

  k_combine_all<<<dim3(64,64),256,0,stream>>>(A, W1a, W1b, W2, C1, C2t, C3t, r);
  k_sparse_y<<<MM,256,0,stream>>>(seqs, C1, y);
  k_diagdeg<<<2048,256,0,stream>>>(C1, C2t, r, diag1, dinv);
  k_gemm_sk<<<1280,256,0,stream>>>(y, C2t, part);               // G2: y @ C2
  k_epi<1><<<dim3(2560,2),256,0,stream>>>(part, seqs, diag1, dinv, IB, u);
  k_gemm_sk<<<1280,256,0,stream>>>(u, C3t, part);               // G3: u @ C3
  u16* e = y;                                                   // y dead, alias as e
  k_epi<2><<<dim3(2560,2),256,0,stream>>>(part, seqs, diag1, dinv, IB, e);
  k_cvt<<<1088,256,0,stream>>>(linw, whh, linwb, whhb);
  k_lin<<<dim3(10,2,32),256,0,stream>>>(e, linwb, encr);
  k_proj<<<320,256,0,stream>>>(encr, linb, pw, pb, bask);
  k_xhat<<<1280,256,0,stream>>>(bask, wih, bih, bhh, xh);
  k_lstm<<<1,512,0,stream>>>(xh, whhb, h0, c0, slen, last);
  k_final<<<dim3(16,32),256,0,stream>>>(last, h2w, IB, (float*)d_out);
}